// Round 1
// baseline (592.032 us; speedup 1.0000x reference)
//
#include <hip/hip_runtime.h>

#define Bn 2
#define Cn 32
#define Wn 96
#define Hn 96
#define Zn 64
#define ROWS (Bn*Wn*Hn)        // 18432
#define CHS (Wn*Hn*Zn)         // 589824
#define FPAD 68
#define NRED ((float)(Bn*Wn*Hn*Zn))  // 1179648

// One block per (b,w,h) row. Computes theta/phi/g, z-attention, residual+mask,
// W-conv; writes pre-BN output to `out` and per-row channel sums/sumsq to `part`.
__global__ __launch_bounds__(256) void k1_row(
    const float* __restrict__ x, const float* __restrict__ spacings,
    const float* __restrict__ theta_w, const float* __restrict__ theta_b,
    const float* __restrict__ phi_w, const float* __restrict__ phi_b,
    const float* __restrict__ g_w, const float* __restrict__ g_b,
    const float* __restrict__ Ww, const float* __restrict__ Wb,
    float* __restrict__ out, float* __restrict__ part)
{
    __shared__ float xs[Cn*Zn];   // x row; reused for res
    __shared__ float ts[Cn*Zn];
    __shared__ float ps[Cn*Zn];
    __shared__ float gs[Cn*Zn];
    __shared__ float fs[Zn*FPAD];
    __shared__ float w_th[Cn*Cn], w_ph[Cn*Cn], w_W[Cn*Cn];
    __shared__ float smallv[224];
    __shared__ float csum[Cn], csq[Cn];

    const int t = threadIdx.x;
    const int lane = t & 63;
    const int wv = t >> 6;
    const int row = blockIdx.x;
    const int b = row / (Wn*Hn);
    const int wh = row - b*(Wn*Hn);
    const int base = b*Cn*CHS + wh*Zn;

    // stage weights
    for (int i = t; i < Cn*Cn; i += 256) {
        w_th[i] = theta_w[i];
        w_ph[i] = phi_w[i];
        w_W[i]  = Ww[i];
    }
    if (t < 96) smallv[t] = g_w[t];
    else if (t < 128) smallv[t] = theta_b[t-96];
    else if (t < 160) smallv[t] = phi_b[t-128];
    else if (t < 192) smallv[t] = g_b[t-160];
    else if (t < 224) smallv[t] = Wb[t-192];

    // stage x row: xs[c*64+z]
    #pragma unroll
    for (int it = 0; it < 8; ++it) {
        const int idx = it*256 + t;
        const int c = idx >> 6;
        xs[idx] = x[base + c*CHS + lane];
    }
    __syncthreads();

    const float* gw  = smallv;
    const float* bth = smallv + 96;
    const float* bph = smallv + 128;
    const float* gb  = smallv + 160;
    const float* bW  = smallv + 192;

    // per-thread x column at z=lane
    float xz[Cn];
    #pragma unroll
    for (int c = 0; c < Cn; ++c) xz[c] = xs[c*64 + lane];

    // theta / phi (1x1x1 convs) + depthwise g conv along z
    #pragma unroll
    for (int it = 0; it < 8; ++it) {
        const int idx = it*256 + t;
        const int c = it*4 + wv;
        float at = bth[c], ap = bph[c];
        #pragma unroll
        for (int cc = 0; cc < Cn; cc += 4) {
            const float4 wt = *(const float4*)&w_th[c*Cn+cc];
            const float4 wp = *(const float4*)&w_ph[c*Cn+cc];
            at = fmaf(wt.x, xz[cc],   at); at = fmaf(wt.y, xz[cc+1], at);
            at = fmaf(wt.z, xz[cc+2], at); at = fmaf(wt.w, xz[cc+3], at);
            ap = fmaf(wp.x, xz[cc],   ap); ap = fmaf(wp.y, xz[cc+1], ap);
            ap = fmaf(wp.z, xz[cc+2], ap); ap = fmaf(wp.w, xz[cc+3], ap);
        }
        ts[idx] = at; ps[idx] = ap;
        const float xm = (lane > 0)  ? xs[c*64 + lane - 1] : 0.f;
        const float xp = (lane < 63) ? xs[c*64 + lane + 1] : 0.f;
        gs[idx] = fmaf(gw[c*3], xm, fmaf(gw[c*3+1], xz[c], fmaf(gw[c*3+2], xp, gb[c])));
    }
    __syncthreads();

    // scores f[z][y] = sum_ic t[ic][z]*p[ic][y]; softmax over y (4 lanes per z)
    const int zf = t >> 2;
    const int jf = t & 3;
    float tz[Cn];
    #pragma unroll
    for (int ic = 0; ic < Cn; ++ic) tz[ic] = ts[ic*64 + zf];
    float facc[16];
    #pragma unroll
    for (int y = 0; y < 16; ++y) facc[y] = 0.f;
    #pragma unroll
    for (int ic = 0; ic < Cn; ++ic) {
        const float tv = tz[ic];
        #pragma unroll
        for (int k = 0; k < 4; ++k) {
            const float4 pv = *(const float4*)&ps[ic*64 + jf*16 + 4*k];
            facc[4*k]   = fmaf(tv, pv.x, facc[4*k]);
            facc[4*k+1] = fmaf(tv, pv.y, facc[4*k+1]);
            facc[4*k+2] = fmaf(tv, pv.z, facc[4*k+2]);
            facc[4*k+3] = fmaf(tv, pv.w, facc[4*k+3]);
        }
    }
    float m = facc[0];
    #pragma unroll
    for (int y = 1; y < 16; ++y) m = fmaxf(m, facc[y]);
    m = fmaxf(m, __shfl_xor(m, 1));
    m = fmaxf(m, __shfl_xor(m, 2));
    float ssum = 0.f;
    #pragma unroll
    for (int y = 0; y < 16; ++y) { facc[y] = __expf(facc[y] - m); ssum += facc[y]; }
    ssum += __shfl_xor(ssum, 1);
    ssum += __shfl_xor(ssum, 2);
    const float inv = 1.0f / ssum;
    #pragma unroll
    for (int k = 0; k < 4; ++k) {
        float4 av;
        av.x = facc[4*k]*inv; av.y = facc[4*k+1]*inv;
        av.z = facc[4*k+2]*inv; av.w = facc[4*k+3]*inv;
        *(float4*)&fs[zf*FPAD + jf*16 + 4*k] = av;
    }
    __syncthreads();

    // y[c][z] = sum_y a[z][y]*gx[c][y]; res = mask ? y+x : x  (in-place into xs)
    float az[64];
    #pragma unroll
    for (int k = 0; k < 16; ++k) {
        const float4 av = *(const float4*)&fs[lane*FPAD + 4*k];
        az[4*k] = av.x; az[4*k+1] = av.y; az[4*k+2] = av.z; az[4*k+3] = av.w;
    }
    const bool msk = spacings[b*3 + 2] <= 1.5f;
    #pragma unroll
    for (int it = 0; it < 8; ++it) {
        const int idx = it*256 + t;
        const int c = it*4 + wv;
        float acc = 0.f;
        #pragma unroll
        for (int k = 0; k < 16; ++k) {
            const float4 gv = *(const float4*)&gs[c*64 + 4*k];
            acc = fmaf(az[4*k],   gv.x, acc);
            acc = fmaf(az[4*k+1], gv.y, acc);
            acc = fmaf(az[4*k+2], gv.z, acc);
            acc = fmaf(az[4*k+3], gv.w, acc);
        }
        xs[idx] = msk ? (acc + xz[c]) : xz[c];
    }
    __syncthreads();

    // W conv (pre-BN) + per-channel sum/sumsq (wave-reduce; (it,wave) -> unique o)
    float rz[Cn];
    #pragma unroll
    for (int c = 0; c < Cn; ++c) rz[c] = xs[c*64 + lane];
    #pragma unroll
    for (int it = 0; it < 8; ++it) {
        const int o = it*4 + wv;
        float acc = bW[o];
        #pragma unroll
        for (int cc = 0; cc < Cn; cc += 4) {
            const float4 w4 = *(const float4*)&w_W[o*Cn+cc];
            acc = fmaf(w4.x, rz[cc],   acc); acc = fmaf(w4.y, rz[cc+1], acc);
            acc = fmaf(w4.z, rz[cc+2], acc); acc = fmaf(w4.w, rz[cc+3], acc);
        }
        out[base + o*CHS + lane] = acc;
        float s1 = acc, s2 = acc*acc;
        #pragma unroll
        for (int off = 32; off >= 1; off >>= 1) {
            s1 += __shfl_xor(s1, off);
            s2 += __shfl_xor(s2, off);
        }
        if (lane == 0) { csum[o] = s1; csq[o] = s2; }
    }
    __syncthreads();
    if (t < 64) part[row*64 + t] = (t < 32) ? csum[t] : csq[t-32];
}

// stage 2a: 256 blocks reduce 72 rows each
__global__ __launch_bounds__(256) void k2a(const float* __restrict__ part,
                                           float* __restrict__ part2)
{
    __shared__ float red[4][64];
    const int t = threadIdx.x, lane = t & 63, grp = t >> 6;
    const int p = blockIdx.x;
    float s = 0.f;
    for (int k = 0; k < 18; ++k) s += part[(p*72 + grp + 4*k)*64 + lane];
    red[grp][lane] = s;
    __syncthreads();
    if (t < 64) part2[p*64 + t] = red[0][t] + red[1][t] + red[2][t] + red[3][t];
}

// stage 2b: final reduce + BN scale/shift
__global__ __launch_bounds__(256) void k2b(const float* __restrict__ part2,
    const float* __restrict__ gamma, const float* __restrict__ beta,
    float* __restrict__ sc)
{
    __shared__ float red[4][64];
    __shared__ float tot[64];
    const int t = threadIdx.x, lane = t & 63, grp = t >> 6;
    float s = 0.f;
    for (int k = 0; k < 64; ++k) s += part2[(grp + 4*k)*64 + lane];
    red[grp][lane] = s;
    __syncthreads();
    if (t < 64) tot[t] = red[0][t] + red[1][t] + red[2][t] + red[3][t];
    __syncthreads();
    if (t < 32) {
        const float mean = tot[t] / NRED;
        const float var  = tot[32+t] / NRED - mean*mean;
        const float rstd = rsqrtf(var + 1e-5f);
        const float scale = gamma[t] * rstd;
        sc[t]      = scale;
        sc[32+t]   = fmaf(-mean, scale, beta[t]);
    }
}

// stage 3: in-place affine normalize of d_out
__global__ __launch_bounds__(256) void k3_norm(float* __restrict__ out,
                                               const float* __restrict__ sc)
{
    __shared__ float s[64];
    if (threadIdx.x < 64) s[threadIdx.x] = sc[threadIdx.x];
    __syncthreads();
    const int total4 = Bn*Cn*CHS/4;   // 9437184
    const int Q = CHS/4;              // 147456
    for (int i = blockIdx.x*256 + threadIdx.x; i < total4; i += gridDim.x*256) {
        float4 v = ((const float4*)out)[i];
        const int c = (i / Q) & 31;
        const float scale = s[c], shift = s[32+c];
        v.x = fmaf(v.x, scale, shift);
        v.y = fmaf(v.y, scale, shift);
        v.z = fmaf(v.z, scale, shift);
        v.w = fmaf(v.w, scale, shift);
        ((float4*)out)[i] = v;
    }
}

extern "C" void kernel_launch(void* const* d_in, const int* in_sizes, int n_in,
                              void* d_out, int out_size, void* d_ws, size_t ws_size,
                              hipStream_t stream) {
    const float* x        = (const float*)d_in[0];
    const float* spacings = (const float*)d_in[1];
    const float* theta_w  = (const float*)d_in[2];
    const float* theta_b  = (const float*)d_in[3];
    const float* phi_w    = (const float*)d_in[4];
    const float* phi_b    = (const float*)d_in[5];
    const float* g_w      = (const float*)d_in[6];
    const float* g_b      = (const float*)d_in[7];
    const float* Ww       = (const float*)d_in[8];
    const float* Wb       = (const float*)d_in[9];
    const float* gamma    = (const float*)d_in[10];
    const float* beta     = (const float*)d_in[11];
    float* out   = (float*)d_out;
    float* part  = (float*)d_ws;            // ROWS*64 floats
    float* part2 = part + ROWS*64;          // 256*64 floats
    float* sc    = part2 + 256*64;          // 64 floats

    hipLaunchKernelGGL(k1_row, dim3(ROWS), dim3(256), 0, stream,
                       x, spacings, theta_w, theta_b, phi_w, phi_b,
                       g_w, g_b, Ww, Wb, out, part);
    hipLaunchKernelGGL(k2a, dim3(256), dim3(256), 0, stream, part, part2);
    hipLaunchKernelGGL(k2b, dim3(1), dim3(256), 0, stream, part2, gamma, beta, sc);
    hipLaunchKernelGGL(k3_norm, dim3(4096), dim3(256), 0, stream, out, sc);
}

// Round 4
// 332.510 us; speedup vs baseline: 1.7805x; 1.7805x over previous
//
#include <hip/hip_runtime.h>
#include <stdint.h>

#define CHS 589824           // W*H*Z
#define ROWS 18432           // B*W*H
#define WHn 9216             // W*H
#define NRED 1179648.0f      // B*W*H*Z

typedef short s16x8 __attribute__((ext_vector_type(8)));
typedef float f32x4v __attribute__((ext_vector_type(4)));

#define MFMA16 __builtin_amdgcn_mfma_f32_16x16x32_bf16

// LDS byte offsets (one copy per block; one block = one (b,w,h) row)
#define OX  0        // X_hi bf16 [z=64][c:40] stride 80B (overlaid by Rt [z][c] in phase3)
#define OXL 5120     // X_lo bf16
#define OG  10240    // G  bf16 [c=32][y:72] stride 144B
#define OT  14848    // T_hi bf16 [z=64][o:40] stride 80B (T transposed)
#define OTL 19968    // T_lo
#define OP  25088    // P_hi bf16 [y=64][o:40] stride 80B
#define OPL 30208    // P_lo
#define OA  35328    // A' bf16 [z=64][y:72] stride 144B (overlaid by Ot f32 [z=64][33] stride 132B)
#define LDSZ 44544

static __device__ __forceinline__ uint16_t bfh(float v) {
    union { __bf16 h; uint16_t u; } c; c.h = (__bf16)v; return c.u;
}
static __device__ __forceinline__ float bf2f(uint16_t u) {
    union { uint32_t x; float f; } c; c.x = (uint32_t)u << 16; return c.f;
}
static __device__ __forceinline__ uint32_t pk2u(uint16_t a, uint16_t b) {
    return (uint32_t)a | ((uint32_t)b << 16);
}
static __device__ __forceinline__ uint32_t pkbf(float a, float b) {
    return pk2u(bfh(a), bfh(b));
}

// hi+lo A-frags of a row-major [16*2][32] f32 weight matrix.
// lane reads rows (l&15)+16*mt, cols 8*(l>>4)..+8 (same k-convention as all B-frags)
static __device__ __forceinline__ void wfrag2(const float* __restrict__ Wp, int mt, int l15, int kb,
                                              s16x8& hi, s16x8& lo) {
    const float* p = Wp + (l15 + 16*mt)*32 + 8*kb;
    const float4 f0 = *(const float4*)p;
    const float4 f1 = *(const float4*)(p + 4);
    float f[8] = {f0.x, f0.y, f0.z, f0.w, f1.x, f1.y, f1.z, f1.w};
    union { uint32_t u[4]; s16x8 v; } rh, rl;
    #pragma unroll
    for (int i = 0; i < 4; ++i) {
        const uint16_t h0 = bfh(f[2*i]), h1 = bfh(f[2*i+1]);
        rh.u[i] = pk2u(h0, h1);
        rl.u[i] = pk2u(bfh(f[2*i] - bf2f(h0)), bfh(f[2*i+1] - bf2f(h1)));
    }
    hi = rh.v; lo = rl.v;
}

__global__ __launch_bounds__(256) void k1_row(
    const float* __restrict__ x, const float* __restrict__ spacings,
    const float* __restrict__ theta_w, const float* __restrict__ theta_b,
    const float* __restrict__ phi_w, const float* __restrict__ phi_b,
    const float* __restrict__ g_w, const float* __restrict__ g_b,
    const float* __restrict__ Ww, const float* __restrict__ Wb,
    float* __restrict__ out, float* __restrict__ part)
{
    __shared__ __align__(16) char lds[LDSZ];
    const int t = threadIdx.x;
    const int wv = t >> 6, l = t & 63;
    const int l15 = l & 15, kb = l >> 4;
    const int row = blockIdx.x;
    const int b = row / WHn, wh = row - b*WHn;
    const long base = (long)b*32*CHS + (long)wh*64;
    const int zr = 16*wv + l15;      // this wave's z-column for phases 2-4

    // ===== phase 0: load x column z=l, build X_hi/X_lo (bf16) and G =====
    #pragma unroll
    for (int k = 0; k < 4; ++k) {
        const int c0 = 8*k + 2*wv;
        const float v0 = x[base + (long)c0*CHS + l];
        const float v1 = x[base + (long)(c0+1)*CHS + l];
        const uint16_t h0 = bfh(v0), h1 = bfh(v1);
        *(uint32_t*)(lds + OX  + l*80 + c0*2) = pk2u(h0, h1);
        *(uint32_t*)(lds + OXL + l*80 + c0*2) = pk2u(bfh(v0 - bf2f(h0)), bfh(v1 - bf2f(h1)));
        #pragma unroll
        for (int e = 0; e < 2; ++e) {
            const int c = c0 + e;
            const float v = e ? v1 : v0;
            float xm = __shfl_up(v, 1);   if (l == 0)  xm = 0.f;
            float xp = __shfl_down(v, 1); if (l == 63) xp = 0.f;
            const float g = g_w[3*c]*xm + g_w[3*c+1]*v + g_w[3*c+2]*xp + g_b[c];
            const float gn = __shfl_xor(g, 1);
            if (!(l & 1))
                *(uint32_t*)(lds + OG + c*144 + l*2) = pkbf(g, gn);  // pk(y=l, y=l+1)
        }
    }
    __syncthreads();

    // ===== phase 1: T = Th*X+tb (waves 0,1) / P = Ph*X+pb (waves 2,3), split-bf16 =====
    {
        const float* wmp = (wv < 2) ? theta_w : phi_w;
        const float* wbp = (wv < 2) ? theta_b : phi_b;
        const int    dst  = (wv < 2) ? OT  : OP;
        const int    dstL = (wv < 2) ? OTL : OPL;
        const int    ntb = (wv & 1) * 2;
        s16x8 a0h, a0l, a1h, a1l;
        wfrag2(wmp, 0, l15, kb, a0h, a0l);
        wfrag2(wmp, 1, l15, kb, a1h, a1l);
        const float4 b0 = *(const float4*)(wbp + 4*kb);        // rows 4kb..+3 (mt=0)
        const float4 b1 = *(const float4*)(wbp + 16 + 4*kb);   // mt=1
        #pragma unroll
        for (int n2 = 0; n2 < 2; ++n2) {
            const int z = 16*(ntb + n2) + l15;
            const s16x8 bxh = *(const s16x8*)(lds + OX  + z*80 + kb*16);
            const s16x8 bxl = *(const s16x8*)(lds + OXL + z*80 + kb*16);
            f32x4v a0; a0[0]=b0.x; a0[1]=b0.y; a0[2]=b0.z; a0[3]=b0.w;
            f32x4v a1; a1[0]=b1.x; a1[1]=b1.y; a1[2]=b1.z; a1[3]=b1.w;
            a0 = MFMA16(a0h, bxh, a0, 0, 0, 0);
            a0 = MFMA16(a0h, bxl, a0, 0, 0, 0);
            a0 = MFMA16(a0l, bxh, a0, 0, 0, 0);
            a1 = MFMA16(a1h, bxh, a1, 0, 0, 0);
            a1 = MFMA16(a1h, bxl, a1, 0, 0, 0);
            a1 = MFMA16(a1l, bxh, a1, 0, 0, 0);
            // store transposed hi+lo: dst[z][o], o = 16*mt + 4*kb + r
            uint16_t h[8]; float lo[8];
            #pragma unroll
            for (int r = 0; r < 4; ++r) {
                h[r]   = bfh(a0[r]); lo[r]   = a0[r] - bf2f(h[r]);
                h[4+r] = bfh(a1[r]); lo[4+r] = a1[r] - bf2f(h[4+r]);
            }
            *(uint32_t*)(lds + dst  + z*80 + (4*kb)*2)          = pk2u(h[0], h[1]);
            *(uint32_t*)(lds + dst  + z*80 + (4*kb)*2 + 4)      = pk2u(h[2], h[3]);
            *(uint32_t*)(lds + dst  + z*80 + (16 + 4*kb)*2)     = pk2u(h[4], h[5]);
            *(uint32_t*)(lds + dst  + z*80 + (16 + 4*kb)*2 + 4) = pk2u(h[6], h[7]);
            *(uint32_t*)(lds + dstL + z*80 + (4*kb)*2)          = pkbf(lo[0], lo[1]);
            *(uint32_t*)(lds + dstL + z*80 + (4*kb)*2 + 4)      = pkbf(lo[2], lo[3]);
            *(uint32_t*)(lds + dstL + z*80 + (16 + 4*kb)*2)     = pkbf(lo[4], lo[5]);
            *(uint32_t*)(lds + dstL + z*80 + (16 + 4*kb)*2 + 4) = pkbf(lo[6], lo[7]);
        }
    }
    __syncthreads();

    // ===== phase 2: F' = P^T * T (split-bf16), softmax over y =====
    {
        const s16x8 bth = *(const s16x8*)(lds + OT  + zr*80 + kb*16);   // B[k=o][n=z]
        const s16x8 btl = *(const s16x8*)(lds + OTL + zr*80 + kb*16);
        f32x4v Fq[4];
        #pragma unroll
        for (int yt = 0; yt < 4; ++yt) {
            const s16x8 pah = *(const s16x8*)(lds + OP  + (16*yt + l15)*80 + kb*16); // A[y][o]
            const s16x8 pal = *(const s16x8*)(lds + OPL + (16*yt + l15)*80 + kb*16);
            f32x4v zz; zz[0]=0.f; zz[1]=0.f; zz[2]=0.f; zz[3]=0.f;
            zz = MFMA16(pah, bth, zz, 0, 0, 0);
            zz = MFMA16(pah, btl, zz, 0, 0, 0);
            zz = MFMA16(pal, bth, zz, 0, 0, 0);
            Fq[yt] = zz;   // F'[y=16yt+4kb+r][z=zr]
        }
        float mx = -3.4e38f;
        #pragma unroll
        for (int yt = 0; yt < 4; ++yt)
            #pragma unroll
            for (int r = 0; r < 4; ++r) mx = fmaxf(mx, Fq[yt][r]);
        mx = fmaxf(mx, __shfl_xor(mx, 16));
        mx = fmaxf(mx, __shfl_xor(mx, 32));
        float p[4][4]; float sum = 0.f;
        #pragma unroll
        for (int yt = 0; yt < 4; ++yt)
            #pragma unroll
            for (int r = 0; r < 4; ++r) { p[yt][r] = __expf(Fq[yt][r] - mx); sum += p[yt][r]; }
        sum += __shfl_xor(sum, 16);
        sum += __shfl_xor(sum, 32);
        const float inv = 1.0f / sum;
        #pragma unroll
        for (int yt = 0; yt < 4; ++yt) {
            *(uint32_t*)(lds + OA + zr*144 + (16*yt + 4*kb)*2)     = pkbf(p[yt][0]*inv, p[yt][1]*inv);
            *(uint32_t*)(lds + OA + zr*144 + (16*yt + 4*kb)*2 + 4) = pkbf(p[yt][2]*inv, p[yt][3]*inv);
        }
    }
    // no barrier needed: phase 3 reads only this wave's A' rows + G (barrier 0 covers G)

    // ===== phase 3: Y = G * A'^T, residual+mask, store Rt =====
    {
        f32x4v Yq[2];
        #pragma unroll
        for (int r = 0; r < 4; ++r) { Yq[0][r] = 0.f; Yq[1][r] = 0.f; }
        #pragma unroll
        for (int ks = 0; ks < 2; ++ks) {
            const s16x8 bA = *(const s16x8*)(lds + OA + zr*144 + (32*ks + 8*kb)*2); // B[k=y][n=z]
            #pragma unroll
            for (int mt = 0; mt < 2; ++mt) {
                const s16x8 gA = *(const s16x8*)(lds + OG + (16*mt + l15)*144 + (32*ks + 8*kb)*2);
                Yq[mt] = MFMA16(gA, bA, Yq[mt], 0, 0, 0);
            }
        }
        const bool msk = spacings[b*3 + 2] <= 1.5f;
        #pragma unroll
        for (int mt = 0; mt < 2; ++mt) {
            float rv[4];
            #pragma unroll
            for (int r = 0; r < 4; ++r) {
                const int c = 16*mt + 4*kb + r;
                const float xv = x[base + (long)c*CHS + zr];   // f32 residual (L2-hot)
                rv[r] = msk ? (Yq[mt][r] + xv) : xv;
            }
            *(uint32_t*)(lds + OX + zr*80 + (16*mt + 4*kb)*2)     = pkbf(rv[0], rv[1]); // Rt[z][c]
            *(uint32_t*)(lds + OX + zr*80 + (16*mt + 4*kb)*2 + 4) = pkbf(rv[2], rv[3]);
        }
    }
    __syncthreads();   // Ot (phase4) overlays A' rows that neighbors may still read

    // ===== phase 4: O = W * R + wb -> Ot f32 [z][33] =====
    {
        const s16x8 bR = *(const s16x8*)(lds + OX + zr*80 + kb*16);  // B[k=c][n=z]
        #pragma unroll
        for (int mt = 0; mt < 2; ++mt) {
            s16x8 aWh, aWl;
            wfrag2(Ww, mt, l15, kb, aWh, aWl);
            const float4 wb4 = *(const float4*)(Wb + 16*mt + 4*kb);
            f32x4v acc; acc[0]=wb4.x; acc[1]=wb4.y; acc[2]=wb4.z; acc[3]=wb4.w;
            acc = MFMA16(aWh, bR, acc, 0, 0, 0);
            #pragma unroll
            for (int r = 0; r < 4; ++r)
                *(float*)(lds + OA + zr*132 + (16*mt + 4*kb + r)*4) = acc[r];
        }
    }
    __syncthreads();

    // ===== phase 5: coalesced store + BN partials =====
    #pragma unroll
    for (int k = 0; k < 8; ++k) {
        const int o = wv + 4*k;
        const float v = *(const float*)(lds + OA + l*132 + o*4);
        out[base + (long)o*CHS + l] = v;
        float s1 = v, s2 = v*v;
        #pragma unroll
        for (int off = 32; off >= 1; off >>= 1) {
            s1 += __shfl_xor(s1, off);
            s2 += __shfl_xor(s2, off);
        }
        if (l == 0) {
            part[row*64 + o]      = s1;
            part[row*64 + 32 + o] = s2;
        }
    }
}

// stage 2a: 256 blocks reduce 72 rows each
__global__ __launch_bounds__(256) void k2a(const float* __restrict__ part,
                                           float* __restrict__ part2)
{
    __shared__ float red[4][64];
    const int t = threadIdx.x, lane = t & 63, grp = t >> 6;
    const int p = blockIdx.x;
    float s = 0.f;
    for (int k = 0; k < 18; ++k) s += part[(p*72 + grp + 4*k)*64 + lane];
    red[grp][lane] = s;
    __syncthreads();
    if (t < 64) part2[p*64 + t] = red[0][t] + red[1][t] + red[2][t] + red[3][t];
}

// stage 2b: final reduce + BN scale/shift
__global__ __launch_bounds__(256) void k2b(const float* __restrict__ part2,
    const float* __restrict__ gamma, const float* __restrict__ beta,
    float* __restrict__ sc)
{
    __shared__ float red[4][64];
    __shared__ float tot[64];
    const int t = threadIdx.x, lane = t & 63, grp = t >> 6;
    float s = 0.f;
    for (int k = 0; k < 64; ++k) s += part2[(grp + 4*k)*64 + lane];
    red[grp][lane] = s;
    __syncthreads();
    if (t < 64) tot[t] = red[0][t] + red[1][t] + red[2][t] + red[3][t];
    __syncthreads();
    if (t < 32) {
        const float mean = tot[t] / NRED;
        const float var  = tot[32+t] / NRED - mean*mean;
        const float rstd = rsqrtf(var + 1e-5f);
        const float scale = gamma[t] * rstd;
        sc[t]    = scale;
        sc[32+t] = fmaf(-mean, scale, beta[t]);
    }
}

// stage 3: in-place affine normalize of d_out
__global__ __launch_bounds__(256) void k3_norm(float* __restrict__ out,
                                               const float* __restrict__ sc)
{
    __shared__ float s[64];
    if (threadIdx.x < 64) s[threadIdx.x] = sc[threadIdx.x];
    __syncthreads();
    const int total4 = 2*32*CHS/4;
    const int Q = CHS/4;
    for (int i = blockIdx.x*256 + threadIdx.x; i < total4; i += gridDim.x*256) {
        float4 v = ((const float4*)out)[i];
        const int c = (i / Q) & 31;
        const float scale = s[c], shift = s[32+c];
        v.x = fmaf(v.x, scale, shift);
        v.y = fmaf(v.y, scale, shift);
        v.z = fmaf(v.z, scale, shift);
        v.w = fmaf(v.w, scale, shift);
        ((float4*)out)[i] = v;
    }
}

extern "C" void kernel_launch(void* const* d_in, const int* in_sizes, int n_in,
                              void* d_out, int out_size, void* d_ws, size_t ws_size,
                              hipStream_t stream) {
    const float* x        = (const float*)d_in[0];
    const float* spacings = (const float*)d_in[1];
    const float* theta_w  = (const float*)d_in[2];
    const float* theta_b  = (const float*)d_in[3];
    const float* phi_w    = (const float*)d_in[4];
    const float* phi_b    = (const float*)d_in[5];
    const float* g_w      = (const float*)d_in[6];
    const float* g_b      = (const float*)d_in[7];
    const float* Ww       = (const float*)d_in[8];
    const float* Wb       = (const float*)d_in[9];
    const float* gamma    = (const float*)d_in[10];
    const float* beta     = (const float*)d_in[11];
    float* out   = (float*)d_out;
    float* part  = (float*)d_ws;            // ROWS*64 floats
    float* part2 = part + ROWS*64;          // 256*64 floats
    float* sc    = part2 + 256*64;          // 64 floats

    hipLaunchKernelGGL(k1_row, dim3(ROWS), dim3(256), 0, stream,
                       x, spacings, theta_w, theta_b, phi_w, phi_b,
                       g_w, g_b, Ww, Wb, out, part);
    hipLaunchKernelGGL(k2a, dim3(256), dim3(256), 0, stream, part, part2);
    hipLaunchKernelGGL(k2b, dim3(1), dim3(256), 0, stream, part2, gamma, beta, sc);
    hipLaunchKernelGGL(k3_norm, dim3(4096), dim3(256), 0, stream, out, sc);
}

// Round 5
// 229.719 us; speedup vs baseline: 2.5772x; 1.4475x over previous
//
#include <hip/hip_runtime.h>
#include <stdint.h>

#define CHS 589824           // W*H*Z
#define ROWS 18432           // B*W*H
#define WHn 9216             // W*H
#define NRED 1179648.0f      // B*W*H*Z

typedef short s16x8 __attribute__((ext_vector_type(8)));
typedef float f32x4v __attribute__((ext_vector_type(4)));

#define MFMA16 __builtin_amdgcn_mfma_f32_16x16x32_bf16

// LDS regions (one block = one (b,w,h) row)
#define OX  0        // X f32 [c=32][z:65] stride 260B  (8320)  - live whole kernel
#define OT  8320     // T_hi bf16 [z=64][o:40] stride 80 (5120)
#define OTL 13440    // T_lo bf16 [z=64][o:36] stride 72 (4608)
#define OP  18048    // P_hi bf16 [y=64][o:40] stride 80 (5120)
#define OPL 23168    // P_lo bf16 [y=64][o:36] stride 72 (4608)
#define OG  27776    // G bf16 [c=32][y:72] stride 144   (4608)
#define LDSZ 32384
// overlays (valid after barrier B3 / B3b):
#define OA  OT       // A' bf16 [z=64][y:72] stride 144 (9216 <= OT+OTL=9728)
#define ORT OP       // Rt bf16 [z=64][c:40] stride 80  (5120)
#define OO  OPL      // Ot f32  [z=64][o:33] stride 132 (8448 <= OPL+OG=9216)

static __device__ __forceinline__ uint16_t bfh(float v) {
    union { __bf16 h; uint16_t u; } c; c.h = (__bf16)v; return c.u;
}
static __device__ __forceinline__ float bf2f(uint16_t u) {
    union { uint32_t x; float f; } c; c.x = (uint32_t)u << 16; return c.f;
}
static __device__ __forceinline__ uint32_t pk2u(uint16_t a, uint16_t b) {
    return (uint32_t)a | ((uint32_t)b << 16);
}
static __device__ __forceinline__ uint32_t pkbf(float a, float b) {
    return pk2u(bfh(a), bfh(b));
}
static __device__ __forceinline__ float bflo(uint32_t u){ union{uint32_t x;float f;} c; c.x = u<<16;          return c.f; }
static __device__ __forceinline__ float bfhi(uint32_t u){ union{uint32_t x;float f;} c; c.x = u & 0xffff0000u; return c.f; }

// hi+lo A-frags of a row-major [16*2][32] f32 weight matrix.
// lane reads rows (l&15)+16*mt, cols 8*kb..+8 (same k-convention as all B-frags)
static __device__ __forceinline__ void wfrag2(const float* __restrict__ Wp, int mt, int l15, int kb,
                                              s16x8& hi, s16x8& lo) {
    const float* p = Wp + (l15 + 16*mt)*32 + 8*kb;
    const float4 f0 = *(const float4*)p;
    const float4 f1 = *(const float4*)(p + 4);
    float f[8] = {f0.x, f0.y, f0.z, f0.w, f1.x, f1.y, f1.z, f1.w};
    union { uint32_t u[4]; s16x8 v; } rh, rl;
    #pragma unroll
    for (int i = 0; i < 4; ++i) {
        const uint16_t h0 = bfh(f[2*i]), h1 = bfh(f[2*i+1]);
        rh.u[i] = pk2u(h0, h1);
        rl.u[i] = pk2u(bfh(f[2*i] - bf2f(h0)), bfh(f[2*i+1] - bf2f(h1)));
    }
    hi = rh.v; lo = rl.v;
}
static __device__ __forceinline__ s16x8 wfragh(const float* __restrict__ Wp, int mt, int l15, int kb) {
    const float* p = Wp + (l15 + 16*mt)*32 + 8*kb;
    const float4 f0 = *(const float4*)p;
    const float4 f1 = *(const float4*)(p + 4);
    union { uint32_t u[4]; s16x8 v; } r;
    r.u[0] = pkbf(f0.x, f0.y); r.u[1] = pkbf(f0.z, f0.w);
    r.u[2] = pkbf(f1.x, f1.y); r.u[3] = pkbf(f1.z, f1.w);
    return r.v;
}

// hi/lo B-frag of X from LDS f32 [c][z:65]: k=c rows 8kb..+8, n=z col
static __device__ __forceinline__ void xfrag(const char* lds, int z, int kb, s16x8& hi, s16x8& lo) {
    union { uint32_t u[4]; s16x8 s; } H, L;
    #pragma unroll
    for (int i = 0; i < 4; ++i) {
        const float v0 = *(const float*)(lds + OX + (8*kb + 2*i    )*260 + z*4);
        const float v1 = *(const float*)(lds + OX + (8*kb + 2*i + 1)*260 + z*4);
        const uint16_t h0 = bfh(v0), h1 = bfh(v1);
        H.u[i] = pk2u(h0, h1);
        L.u[i] = pk2u(bfh(v0 - bf2f(h0)), bfh(v1 - bf2f(h1)));
    }
    hi = H.s; lo = L.s;
}

__global__ __launch_bounds__(256, 5) void k1_row(
    const float* __restrict__ x, const float* __restrict__ spacings,
    const float* __restrict__ theta_w, const float* __restrict__ theta_b,
    const float* __restrict__ phi_w, const float* __restrict__ phi_b,
    const float* __restrict__ g_w, const float* __restrict__ g_b,
    const float* __restrict__ Ww, const float* __restrict__ Wb,
    float* __restrict__ out, float* __restrict__ part)
{
    __shared__ __align__(16) char lds[LDSZ];
    const int t = threadIdx.x;
    const int wv = t >> 6, l = t & 63;
    const int l15 = l & 15, kb = l >> 4;
    const int row = blockIdx.x;
    const int b = row / WHn, wh = row - b*WHn;
    const long base = (long)b*32*CHS + (long)wh*64;
    const int zr = 16*wv + l15;

    // ===== phase 0: stage x -> X f32 [c][z] (conflict-free: lanes along z) =====
    #pragma unroll
    for (int j = 0; j < 8; ++j) {
        const int c = 8*wv + j;
        *(float*)(lds + OX + c*260 + l*4) = x[base + (long)c*CHS + l];
    }
    __syncthreads();   // B1

    // ===== G-compute (own c rows) + phase 1: T/P split-bf16 matmuls =====
    #pragma unroll
    for (int j = 0; j < 8; ++j) {
        const int c = 8*wv + j;
        const float xc = *(const float*)(lds + OX + c*260 + l*4);
        const int lm = (l > 0) ? l-1 : 0, lp = (l < 63) ? l+1 : 63;
        float xm = *(const float*)(lds + OX + c*260 + lm*4);
        float xp = *(const float*)(lds + OX + c*260 + lp*4);
        if (l == 0)  xm = 0.f;
        if (l == 63) xp = 0.f;
        const float g = g_w[3*c]*xm + g_w[3*c+1]*xc + g_w[3*c+2]*xp + g_b[c];
        *(uint16_t*)(lds + OG + c*144 + 2*l) = bfh(g);
    }
    {
        const float* wmp = (wv < 2) ? theta_w : phi_w;
        const float* wbp = (wv < 2) ? theta_b : phi_b;
        const int    dst  = (wv < 2) ? OT  : OP;
        const int    dstL = (wv < 2) ? OTL : OPL;
        const int    ntb = (wv & 1) * 2;
        s16x8 a0h, a0l, a1h, a1l;
        wfrag2(wmp, 0, l15, kb, a0h, a0l);
        wfrag2(wmp, 1, l15, kb, a1h, a1l);
        const float4 b0 = *(const float4*)(wbp + 4*kb);
        const float4 b1 = *(const float4*)(wbp + 16 + 4*kb);
        #pragma unroll
        for (int n2 = 0; n2 < 2; ++n2) {
            const int z = 16*(ntb + n2) + l15;
            s16x8 bxh, bxl;
            xfrag(lds, z, kb, bxh, bxl);
            f32x4v a0; a0[0]=b0.x; a0[1]=b0.y; a0[2]=b0.z; a0[3]=b0.w;
            f32x4v a1; a1[0]=b1.x; a1[1]=b1.y; a1[2]=b1.z; a1[3]=b1.w;
            a0 = MFMA16(a0h, bxh, a0, 0, 0, 0);
            a0 = MFMA16(a0h, bxl, a0, 0, 0, 0);
            a0 = MFMA16(a0l, bxh, a0, 0, 0, 0);
            a1 = MFMA16(a1h, bxh, a1, 0, 0, 0);
            a1 = MFMA16(a1h, bxl, a1, 0, 0, 0);
            a1 = MFMA16(a1l, bxh, a1, 0, 0, 0);
            // transposed store: dst[z][o], o = 16*mt+4*kb+r ; hi b64 + lo b64 per mt
            uint16_t h[8]; float lo[8];
            #pragma unroll
            for (int r = 0; r < 4; ++r) {
                h[r]   = bfh(a0[r]); lo[r]   = a0[r] - bf2f(h[r]);
                h[4+r] = bfh(a1[r]); lo[4+r] = a1[r] - bf2f(h[4+r]);
            }
            union { uint32_t u[2]; uint64_t q; } w0, w1;
            w0.u[0] = pk2u(h[0], h[1]); w0.u[1] = pk2u(h[2], h[3]);
            w1.u[0] = pk2u(h[4], h[5]); w1.u[1] = pk2u(h[6], h[7]);
            *(uint64_t*)(lds + dst + z*80 + 8*kb)      = w0.q;
            *(uint64_t*)(lds + dst + z*80 + 32 + 8*kb) = w1.q;
            w0.u[0] = pkbf(lo[0], lo[1]); w0.u[1] = pkbf(lo[2], lo[3]);
            w1.u[0] = pkbf(lo[4], lo[5]); w1.u[1] = pkbf(lo[6], lo[7]);
            *(uint64_t*)(lds + dstL + z*72 + 8*kb)      = w0.q;
            *(uint64_t*)(lds + dstL + z*72 + 32 + 8*kb) = w1.q;
        }
    }
    __syncthreads();   // B2

    // ===== phase 2a: F' = P^T * T (split-bf16) -> Fq regs =====
    f32x4v Fq[4];
    {
        const s16x8 bth = *(const s16x8*)(lds + OT + zr*80 + kb*16);
        union { uint64_t q[2]; s16x8 s; } TL;
        TL.q[0] = *(const uint64_t*)(lds + OTL + zr*72 + kb*16);
        TL.q[1] = *(const uint64_t*)(lds + OTL + zr*72 + kb*16 + 8);
        const s16x8 btl = TL.s;
        #pragma unroll
        for (int yt = 0; yt < 4; ++yt) {
            const int y = 16*yt + l15;
            const s16x8 pah = *(const s16x8*)(lds + OP + y*80 + kb*16);
            union { uint64_t q[2]; s16x8 s; } PL;
            PL.q[0] = *(const uint64_t*)(lds + OPL + y*72 + kb*16);
            PL.q[1] = *(const uint64_t*)(lds + OPL + y*72 + kb*16 + 8);
            f32x4v zz; zz[0]=0.f; zz[1]=0.f; zz[2]=0.f; zz[3]=0.f;
            zz = MFMA16(pah, bth, zz, 0, 0, 0);
            zz = MFMA16(pah, btl, zz, 0, 0, 0);
            zz = MFMA16(PL.s, bth, zz, 0, 0, 0);
            Fq[yt] = zz;   // F'[y=16yt+4kb+r][z=zr]
        }
    }
    __syncthreads();   // B3 (T/P reads done everywhere -> overlays legal)

    // ===== phase 2b: softmax over y, A' -> OA =====
    {
        float mx = -3.4e38f;
        #pragma unroll
        for (int yt = 0; yt < 4; ++yt)
            #pragma unroll
            for (int r = 0; r < 4; ++r) mx = fmaxf(mx, Fq[yt][r]);
        mx = fmaxf(mx, __shfl_xor(mx, 16));
        mx = fmaxf(mx, __shfl_xor(mx, 32));
        float p[4][4]; float sum = 0.f;
        #pragma unroll
        for (int yt = 0; yt < 4; ++yt)
            #pragma unroll
            for (int r = 0; r < 4; ++r) { p[yt][r] = __expf(Fq[yt][r] - mx); sum += p[yt][r]; }
        sum += __shfl_xor(sum, 16);
        sum += __shfl_xor(sum, 32);
        const float inv = 1.0f / sum;
        #pragma unroll
        for (int yt = 0; yt < 4; ++yt) {
            *(uint32_t*)(lds + OA + zr*144 + (16*yt + 4*kb)*2)     = pkbf(p[yt][0]*inv, p[yt][1]*inv);
            *(uint32_t*)(lds + OA + zr*144 + (16*yt + 4*kb)*2 + 4) = pkbf(p[yt][2]*inv, p[yt][3]*inv);
        }
    }

    // ===== phase 3: Y = G * A'^T, residual(+mask) from X-LDS, Rt -> ORT =====
    {
        f32x4v Yq[2];
        #pragma unroll
        for (int r = 0; r < 4; ++r) { Yq[0][r] = 0.f; Yq[1][r] = 0.f; }
        #pragma unroll
        for (int ks = 0; ks < 2; ++ks) {
            const s16x8 bA = *(const s16x8*)(lds + OA + zr*144 + 64*ks + 16*kb);
            #pragma unroll
            for (int mt = 0; mt < 2; ++mt) {
                const s16x8 gA = *(const s16x8*)(lds + OG + (16*mt + l15)*144 + 64*ks + 16*kb);
                Yq[mt] = MFMA16(gA, bA, Yq[mt], 0, 0, 0);
            }
        }
        const bool msk = spacings[b*3 + 2] <= 1.5f;
        #pragma unroll
        for (int mt = 0; mt < 2; ++mt) {
            float rv[4];
            #pragma unroll
            for (int r = 0; r < 4; ++r) {
                const int c = 16*mt + 4*kb + r;
                const float xv = *(const float*)(lds + OX + c*260 + zr*4);
                rv[r] = msk ? (Yq[mt][r] + xv) : xv;
            }
            union { uint32_t u[2]; uint64_t q; } w;
            w.u[0] = pkbf(rv[0], rv[1]); w.u[1] = pkbf(rv[2], rv[3]);
            *(uint64_t*)(lds + ORT + zr*80 + 32*mt + 8*kb) = w.q;
        }
    }
    __syncthreads();   // B3b (all G reads done -> Ot may overlay OPL+OG)

    // ===== phase 4: O = W * R + wb -> Ot f32 [z][33] =====
    {
        const s16x8 bR = *(const s16x8*)(lds + ORT + zr*80 + kb*16);
        #pragma unroll
        for (int mt = 0; mt < 2; ++mt) {
            const s16x8 aW = wfragh(Ww, mt, l15, kb);
            const float4 wb4 = *(const float4*)(Wb + 16*mt + 4*kb);
            f32x4v acc; acc[0]=wb4.x; acc[1]=wb4.y; acc[2]=wb4.z; acc[3]=wb4.w;
            acc = MFMA16(aW, bR, acc, 0, 0, 0);
            #pragma unroll
            for (int r = 0; r < 4; ++r)
                *(float*)(lds + OO + zr*132 + (16*mt + 4*kb + r)*4) = acc[r];
        }
    }
    __syncthreads();   // B4

    // ===== phase 5: coalesced store + BN partials =====
    #pragma unroll
    for (int k = 0; k < 8; ++k) {
        const int o = wv + 4*k;
        const float v = *(const float*)(lds + OO + l*132 + o*4);
        out[base + (long)o*CHS + l] = v;
        float s1 = v, s2 = v*v;
        #pragma unroll
        for (int off = 32; off >= 1; off >>= 1) {
            s1 += __shfl_xor(s1, off);
            s2 += __shfl_xor(s2, off);
        }
        if (l == 0) {
            part[row*64 + o]      = s1;
            part[row*64 + 32 + o] = s2;
        }
    }
}

// stage 2a: 256 blocks reduce 72 rows each
__global__ __launch_bounds__(256) void k2a(const float* __restrict__ part,
                                           float* __restrict__ part2)
{
    __shared__ float red[4][64];
    const int t = threadIdx.x, lane = t & 63, grp = t >> 6;
    const int p = blockIdx.x;
    float s = 0.f;
    for (int k = 0; k < 18; ++k) s += part[(p*72 + grp + 4*k)*64 + lane];
    red[grp][lane] = s;
    __syncthreads();
    if (t < 64) part2[p*64 + t] = red[0][t] + red[1][t] + red[2][t] + red[3][t];
}

// stage 2b: final reduce + BN scale/shift
__global__ __launch_bounds__(256) void k2b(const float* __restrict__ part2,
    const float* __restrict__ gamma, const float* __restrict__ beta,
    float* __restrict__ sc)
{
    __shared__ float red[4][64];
    __shared__ float tot[64];
    const int t = threadIdx.x, lane = t & 63, grp = t >> 6;
    float s = 0.f;
    for (int k = 0; k < 64; ++k) s += part2[(grp + 4*k)*64 + lane];
    red[grp][lane] = s;
    __syncthreads();
    if (t < 64) tot[t] = red[0][t] + red[1][t] + red[2][t] + red[3][t];
    __syncthreads();
    if (t < 32) {
        const float mean = tot[t] / NRED;
        const float var  = tot[32+t] / NRED - mean*mean;
        const float rstd = rsqrtf(var + 1e-5f);
        const float scale = gamma[t] * rstd;
        sc[t]    = scale;
        sc[32+t] = fmaf(-mean, scale, beta[t]);
    }
}

// stage 3: in-place affine normalize of d_out
__global__ __launch_bounds__(256) void k3_norm(float* __restrict__ out,
                                               const float* __restrict__ sc)
{
    __shared__ float s[64];
    if (threadIdx.x < 64) s[threadIdx.x] = sc[threadIdx.x];
    __syncthreads();
    const int total4 = 2*32*CHS/4;
    const int Q = CHS/4;
    for (int i = blockIdx.x*256 + threadIdx.x; i < total4; i += gridDim.x*256) {
        float4 v = ((const float4*)out)[i];
        const int c = (i / Q) & 31;
        const float scale = s[c], shift = s[32+c];
        v.x = fmaf(v.x, scale, shift);
        v.y = fmaf(v.y, scale, shift);
        v.z = fmaf(v.z, scale, shift);
        v.w = fmaf(v.w, scale, shift);
        ((float4*)out)[i] = v;
    }
}

extern "C" void kernel_launch(void* const* d_in, const int* in_sizes, int n_in,
                              void* d_out, int out_size, void* d_ws, size_t ws_size,
                              hipStream_t stream) {
    const float* x        = (const float*)d_in[0];
    const float* spacings = (const float*)d_in[1];
    const float* theta_w  = (const float*)d_in[2];
    const float* theta_b  = (const float*)d_in[3];
    const float* phi_w    = (const float*)d_in[4];
    const float* phi_b    = (const float*)d_in[5];
    const float* g_w      = (const float*)d_in[6];
    const float* g_b      = (const float*)d_in[7];
    const float* Ww       = (const float*)d_in[8];
    const float* Wb       = (const float*)d_in[9];
    const float* gamma    = (const float*)d_in[10];
    const float* beta     = (const float*)d_in[11];
    float* out   = (float*)d_out;
    float* part  = (float*)d_ws;            // ROWS*64 floats
    float* part2 = part + ROWS*64;          // 256*64 floats
    float* sc    = part2 + 256*64;          // 64 floats

    hipLaunchKernelGGL(k1_row, dim3(ROWS), dim3(256), 0, stream,
                       x, spacings, theta_w, theta_b, phi_w, phi_b,
                       g_w, g_b, Ww, Wb, out, part);
    hipLaunchKernelGGL(k2a, dim3(256), dim3(256), 0, stream, part, part2);
    hipLaunchKernelGGL(k2b, dim3(1), dim3(256), 0, stream, part2, gamma, beta, sc);
    hipLaunchKernelGGL(k3_norm, dim3(4096), dim3(256), 0, stream, out, sc);
}

// Round 6
// 196.183 us; speedup vs baseline: 3.0178x; 1.1709x over previous
//
#include <hip/hip_runtime.h>
#include <stdint.h>

#define CHS 589824           // W*H*Z
#define ROWS 18432           // B*W*H
#define WHn 9216             // W*H
#define NRED 1179648.0f      // B*W*H*Z

typedef short s16x8 __attribute__((ext_vector_type(8)));
typedef float f32x4v __attribute__((ext_vector_type(4)));

#define MFMA16 __builtin_amdgcn_mfma_f32_16x16x32_bf16

// ws layout (bytes): [0,10240) weight frags ; then part/part2/sc (f32)
//   frags: thetaH 0, thetaL 2048, phiH 4096, phiL 6144, Wh 8192
#define WSFRAG 10240

// LDS regions (one block = one (b,w,h) row)
#define OX  0        // X f32 [c=32][z:65] stride 260B (8320) - live whole kernel
#define OT  8320     // T_hi bf16 [z=64][o:36] stride 72 (4608)
#define OTL 12928    // T_lo bf16 [z=64][o:36] stride 72 (4608)
#define OP  17536    // P_hi bf16 [y=64][o:36] stride 72 (4608)
#define OG  22144    // G bf16 [c=32][y:72] stride 144  (4608)
#define LDSZ 26752
// overlays:
#define OA  OT       // A' bf16 [z=64][y:72] stride 144 (9216 == T+TL region)
#define ORT OP       // Rt bf16 [z=64][c:36] stride 72  (4608)
#define OO  OT       // Ot f32  [z=64][o:33] stride 132 (8448 <= 9216), after B3b

static __device__ __forceinline__ uint16_t bfh(float v) {
    union { __bf16 h; uint16_t u; } c; c.h = (__bf16)v; return c.u;
}
static __device__ __forceinline__ float bf2f(uint16_t u) {
    union { uint32_t x; float f; } c; c.x = (uint32_t)u << 16; return c.f;
}
static __device__ __forceinline__ uint32_t pk2u(uint16_t a, uint16_t b) {
    return (uint32_t)a | ((uint32_t)b << 16);
}
static __device__ __forceinline__ uint32_t pkbf(float a, float b) {
    return pk2u(bfh(a), bfh(b));
}

// hi+lo A-frags of a row-major [16*2][32] f32 weight matrix.
// lane reads rows (l&15)+16*mt, cols 8*kb..+8
static __device__ __forceinline__ void wfrag2(const float* __restrict__ Wp, int mt, int l15, int kb,
                                              s16x8& hi, s16x8& lo) {
    const float* p = Wp + (l15 + 16*mt)*32 + 8*kb;
    const float4 f0 = *(const float4*)p;
    const float4 f1 = *(const float4*)(p + 4);
    float f[8] = {f0.x, f0.y, f0.z, f0.w, f1.x, f1.y, f1.z, f1.w};
    union { uint32_t u[4]; s16x8 v; } rh, rl;
    #pragma unroll
    for (int i = 0; i < 4; ++i) {
        const uint16_t h0 = bfh(f[2*i]), h1 = bfh(f[2*i+1]);
        rh.u[i] = pk2u(h0, h1);
        rl.u[i] = pk2u(bfh(f[2*i] - bf2f(h0)), bfh(f[2*i+1] - bf2f(h1)));
    }
    hi = rh.v; lo = rl.v;
}
static __device__ __forceinline__ s16x8 wfragh(const float* __restrict__ Wp, int mt, int l15, int kb) {
    const float* p = Wp + (l15 + 16*mt)*32 + 8*kb;
    const float4 f0 = *(const float4*)p;
    const float4 f1 = *(const float4*)(p + 4);
    union { uint32_t u[4]; s16x8 v; } r;
    r.u[0] = pkbf(f0.x, f0.y); r.u[1] = pkbf(f0.z, f0.w);
    r.u[2] = pkbf(f1.x, f1.y); r.u[3] = pkbf(f1.z, f1.w);
    return r.v;
}

// k0: one block, precompute weight fragments into ws
__global__ __launch_bounds__(256) void k0_frag(
    const float* __restrict__ theta_w, const float* __restrict__ phi_w,
    const float* __restrict__ Ww, char* __restrict__ ws)
{
    const int tid = threadIdx.x;
    const int m = tid >> 7;            // 0 = theta, 1 = phi
    const int r = tid & 127;
    const int mt = r >> 6, l = r & 63;
    s16x8 hi, lo;
    wfrag2(m ? phi_w : theta_w, mt, l & 15, l >> 4, hi, lo);
    *(s16x8*)(ws + m*4096 + (mt*64 + l)*16)        = hi;
    *(s16x8*)(ws + m*4096 + 2048 + (mt*64 + l)*16) = lo;
    if (tid < 128) {
        const int mtw = tid >> 6, lw = tid & 63;
        *(s16x8*)(ws + 8192 + (mtw*64 + lw)*16) = wfragh(Ww, mtw, lw & 15, lw >> 4);
    }
}

// hi/lo B-frag of X from LDS f32 [c][z:65]: k=c rows 8kb..+8, n=z col
static __device__ __forceinline__ void xfrag(const char* lds, int z, int kb, s16x8& hi, s16x8& lo) {
    union { uint32_t u[4]; s16x8 s; } H, L;
    #pragma unroll
    for (int i = 0; i < 4; ++i) {
        const float v0 = *(const float*)(lds + OX + (8*kb + 2*i    )*260 + z*4);
        const float v1 = *(const float*)(lds + OX + (8*kb + 2*i + 1)*260 + z*4);
        const uint16_t h0 = bfh(v0), h1 = bfh(v1);
        H.u[i] = pk2u(h0, h1);
        L.u[i] = pk2u(bfh(v0 - bf2f(h0)), bfh(v1 - bf2f(h1)));
    }
    hi = H.s; lo = L.s;
}
// b128-equivalent read at 8B-aligned stride-72 rows: two b64s
static __device__ __forceinline__ s16x8 rd72(const char* p) {
    union { uint64_t q[2]; s16x8 s; } v;
    v.q[0] = *(const uint64_t*)p;
    v.q[1] = *(const uint64_t*)(p + 8);
    return v.s;
}

__global__ __launch_bounds__(256, 6) void k1_row(
    const float* __restrict__ x, const float* __restrict__ spacings,
    const float* __restrict__ theta_b, const float* __restrict__ phi_b,
    const float* __restrict__ g_w, const float* __restrict__ g_b,
    const float* __restrict__ Wb, const char* __restrict__ frags,
    float* __restrict__ out, float* __restrict__ part)
{
    __shared__ __align__(16) char lds[LDSZ];
    const int t = threadIdx.x;
    const int wv = t >> 6, l = t & 63;
    const int l15 = l & 15, kb = l >> 4;
    const int row = blockIdx.x;
    const int b = row / WHn, wh = row - b*WHn;
    const long base = (long)b*32*CHS + (long)wh*64;
    const int zr = 16*wv + l15;

    // ===== phase 0: stage x -> X f32 [c][z] (conflict-free: lanes along z) =====
    #pragma unroll
    for (int j = 0; j < 8; ++j) {
        const int c = 8*wv + j;
        *(float*)(lds + OX + c*260 + l*4) = x[base + (long)c*CHS + l];
    }
    __syncthreads();   // B1

    // ===== G-compute (own c rows) + phase 1: T split / P split-compute hi-store =====
    #pragma unroll
    for (int j = 0; j < 8; ++j) {
        const int c = 8*wv + j;
        const float xc = *(const float*)(lds + OX + c*260 + l*4);
        const int lm = (l > 0) ? l-1 : 0, lp = (l < 63) ? l+1 : 63;
        float xm = *(const float*)(lds + OX + c*260 + lm*4);
        float xp = *(const float*)(lds + OX + c*260 + lp*4);
        if (l == 0)  xm = 0.f;
        if (l == 63) xp = 0.f;
        const float g = g_w[3*c]*xm + g_w[3*c+1]*xc + g_w[3*c+2]*xp + g_b[c];
        *(uint16_t*)(lds + OG + c*144 + 2*l) = bfh(g);
    }
    {
        const char* fb = frags + ((wv < 2) ? 0 : 4096);
        const float* wbp = (wv < 2) ? theta_b : phi_b;
        const int    dst = (wv < 2) ? OT : OP;
        const bool   doLo = (wv < 2);
        const int    ntb = (wv & 1) * 2;
        const s16x8 a0h = *(const s16x8*)(fb + l*16);
        const s16x8 a0l = *(const s16x8*)(fb + 2048 + l*16);
        const s16x8 a1h = *(const s16x8*)(fb + 1024 + l*16);
        const s16x8 a1l = *(const s16x8*)(fb + 2048 + 1024 + l*16);
        const float4 b0 = *(const float4*)(wbp + 4*kb);
        const float4 b1 = *(const float4*)(wbp + 16 + 4*kb);
        #pragma unroll
        for (int n2 = 0; n2 < 2; ++n2) {
            const int z = 16*(ntb + n2) + l15;
            s16x8 bxh, bxl;
            xfrag(lds, z, kb, bxh, bxl);
            f32x4v a0; a0[0]=b0.x; a0[1]=b0.y; a0[2]=b0.z; a0[3]=b0.w;
            f32x4v a1; a1[0]=b1.x; a1[1]=b1.y; a1[2]=b1.z; a1[3]=b1.w;
            a0 = MFMA16(a0h, bxh, a0, 0, 0, 0);
            a0 = MFMA16(a0h, bxl, a0, 0, 0, 0);
            a0 = MFMA16(a0l, bxh, a0, 0, 0, 0);
            a1 = MFMA16(a1h, bxh, a1, 0, 0, 0);
            a1 = MFMA16(a1h, bxl, a1, 0, 0, 0);
            a1 = MFMA16(a1l, bxh, a1, 0, 0, 0);
            // transposed store: dst[z][o], o = 16*mt+4*kb+r
            uint16_t h[8];
            #pragma unroll
            for (int r = 0; r < 4; ++r) { h[r] = bfh(a0[r]); h[4+r] = bfh(a1[r]); }
            union { uint32_t u[2]; uint64_t q; } w0, w1;
            w0.u[0] = pk2u(h[0], h[1]); w0.u[1] = pk2u(h[2], h[3]);
            w1.u[0] = pk2u(h[4], h[5]); w1.u[1] = pk2u(h[6], h[7]);
            *(uint64_t*)(lds + dst + z*72 + 8*kb)      = w0.q;
            *(uint64_t*)(lds + dst + z*72 + 32 + 8*kb) = w1.q;
            if (doLo) {
                #pragma unroll
                for (int r = 0; r < 4; ++r) {
                    w0.u[0] = r ? w0.u[0] : 0; // keep alive
                }
                union { uint32_t u[2]; uint64_t q; } v0, v1;
                v0.u[0] = pkbf(a0[0]-bf2f(h[0]), a0[1]-bf2f(h[1]));
                v0.u[1] = pkbf(a0[2]-bf2f(h[2]), a0[3]-bf2f(h[3]));
                v1.u[0] = pkbf(a1[0]-bf2f(h[4]), a1[1]-bf2f(h[5]));
                v1.u[1] = pkbf(a1[2]-bf2f(h[6]), a1[3]-bf2f(h[7]));
                *(uint64_t*)(lds + OTL + z*72 + 8*kb)      = v0.q;
                *(uint64_t*)(lds + OTL + z*72 + 32 + 8*kb) = v1.q;
            }
        }
    }
    __syncthreads();   // B2

    // ===== phase 2a: F' = P_hi^T * (T_hi + T_lo) -> Fq regs =====
    f32x4v Fq[4];
    {
        const s16x8 bth = rd72(lds + OT  + zr*72 + kb*16);
        const s16x8 btl = rd72(lds + OTL + zr*72 + kb*16);
        #pragma unroll
        for (int yt = 0; yt < 4; ++yt) {
            const int y = 16*yt + l15;
            const s16x8 pah = rd72(lds + OP + y*72 + kb*16);
            f32x4v zz; zz[0]=0.f; zz[1]=0.f; zz[2]=0.f; zz[3]=0.f;
            zz = MFMA16(pah, bth, zz, 0, 0, 0);
            zz = MFMA16(pah, btl, zz, 0, 0, 0);
            Fq[yt] = zz;   // F'[y=16yt+4kb+r][z=zr]
        }
    }
    __syncthreads();   // B3 (T/P reads done -> A' may overlay T/TL)

    // ===== phase 2b: softmax over y, A' -> OA =====
    {
        float mx = -3.4e38f;
        #pragma unroll
        for (int yt = 0; yt < 4; ++yt)
            #pragma unroll
            for (int r = 0; r < 4; ++r) mx = fmaxf(mx, Fq[yt][r]);
        mx = fmaxf(mx, __shfl_xor(mx, 16));
        mx = fmaxf(mx, __shfl_xor(mx, 32));
        float p[4][4]; float sum = 0.f;
        #pragma unroll
        for (int yt = 0; yt < 4; ++yt)
            #pragma unroll
            for (int r = 0; r < 4; ++r) { p[yt][r] = __expf(Fq[yt][r] - mx); sum += p[yt][r]; }
        sum += __shfl_xor(sum, 16);
        sum += __shfl_xor(sum, 32);
        const float inv = 1.0f / sum;
        #pragma unroll
        for (int yt = 0; yt < 4; ++yt) {
            *(uint32_t*)(lds + OA + zr*144 + (16*yt + 4*kb)*2)     = pkbf(p[yt][0]*inv, p[yt][1]*inv);
            *(uint32_t*)(lds + OA + zr*144 + (16*yt + 4*kb)*2 + 4) = pkbf(p[yt][2]*inv, p[yt][3]*inv);
        }
    }

    // ===== phase 3: Y = G * A'^T, residual(+mask) from X-LDS, Rt -> ORT =====
    {
        f32x4v Yq[2];
        #pragma unroll
        for (int r = 0; r < 4; ++r) { Yq[0][r] = 0.f; Yq[1][r] = 0.f; }
        #pragma unroll
        for (int ks = 0; ks < 2; ++ks) {
            const s16x8 bA = *(const s16x8*)(lds + OA + zr*144 + 64*ks + 16*kb);
            #pragma unroll
            for (int mt = 0; mt < 2; ++mt) {
                const s16x8 gA = *(const s16x8*)(lds + OG + (16*mt + l15)*144 + 64*ks + 16*kb);
                Yq[mt] = MFMA16(gA, bA, Yq[mt], 0, 0, 0);
            }
        }
        const bool msk = spacings[b*3 + 2] <= 1.5f;
        #pragma unroll
        for (int mt = 0; mt < 2; ++mt) {
            float rv[4];
            #pragma unroll
            for (int r = 0; r < 4; ++r) {
                const int c = 16*mt + 4*kb + r;
                const float xv = *(const float*)(lds + OX + c*260 + zr*4);
                rv[r] = msk ? (Yq[mt][r] + xv) : xv;
            }
            union { uint32_t u[2]; uint64_t q; } w;
            w.u[0] = pkbf(rv[0], rv[1]); w.u[1] = pkbf(rv[2], rv[3]);
            *(uint64_t*)(lds + ORT + zr*72 + 32*mt + 8*kb) = w.q;
        }
    }
    __syncthreads();   // B3b (A' reads done -> Ot may overlay OA region)

    // ===== phase 4: O = W * R + wb -> Ot f32 [z][33] =====
    {
        const s16x8 bR = rd72(lds + ORT + zr*72 + kb*16);
        #pragma unroll
        for (int mt = 0; mt < 2; ++mt) {
            const s16x8 aW = *(const s16x8*)(frags + 8192 + (mt*64 + l)*16);
            const float4 wb4 = *(const float4*)(Wb + 16*mt + 4*kb);
            f32x4v acc; acc[0]=wb4.x; acc[1]=wb4.y; acc[2]=wb4.z; acc[3]=wb4.w;
            acc = MFMA16(aW, bR, acc, 0, 0, 0);
            #pragma unroll
            for (int r = 0; r < 4; ++r)
                *(float*)(lds + OO + zr*132 + (16*mt + 4*kb + r)*4) = acc[r];
        }
    }
    __syncthreads();   // B4

    // ===== phase 5: coalesced store + BN partials =====
    #pragma unroll
    for (int k = 0; k < 8; ++k) {
        const int o = wv + 4*k;
        const float v = *(const float*)(lds + OO + l*132 + o*4);
        out[base + (long)o*CHS + l] = v;
        float s1 = v, s2 = v*v;
        #pragma unroll
        for (int off = 32; off >= 1; off >>= 1) {
            s1 += __shfl_xor(s1, off);
            s2 += __shfl_xor(s2, off);
        }
        if (l == 0) {
            part[row*64 + o]      = s1;
            part[row*64 + 32 + o] = s2;
        }
    }
}

// stage 2a: 256 blocks reduce 72 rows each
__global__ __launch_bounds__(256) void k2a(const float* __restrict__ part,
                                           float* __restrict__ part2)
{
    __shared__ float red[4][64];
    const int t = threadIdx.x, lane = t & 63, grp = t >> 6;
    const int p = blockIdx.x;
    float s = 0.f;
    for (int k = 0; k < 18; ++k) s += part[(p*72 + grp + 4*k)*64 + lane];
    red[grp][lane] = s;
    __syncthreads();
    if (t < 64) part2[p*64 + t] = red[0][t] + red[1][t] + red[2][t] + red[3][t];
}

// stage 2b: final reduce + BN scale/shift
__global__ __launch_bounds__(256) void k2b(const float* __restrict__ part2,
    const float* __restrict__ gamma, const float* __restrict__ beta,
    float* __restrict__ sc)
{
    __shared__ float red[4][64];
    __shared__ float tot[64];
    const int t = threadIdx.x, lane = t & 63, grp = t >> 6;
    float s = 0.f;
    for (int k = 0; k < 64; ++k) s += part2[(grp + 4*k)*64 + lane];
    red[grp][lane] = s;
    __syncthreads();
    if (t < 64) tot[t] = red[0][t] + red[1][t] + red[2][t] + red[3][t];
    __syncthreads();
    if (t < 32) {
        const float mean = tot[t] / NRED;
        const float var  = tot[32+t] / NRED - mean*mean;
        const float rstd = rsqrtf(var + 1e-5f);
        const float scale = gamma[t] * rstd;
        sc[t]    = scale;
        sc[32+t] = fmaf(-mean, scale, beta[t]);
    }
}

// stage 3: in-place affine normalize of d_out
__global__ __launch_bounds__(256) void k3_norm(float* __restrict__ out,
                                               const float* __restrict__ sc)
{
    __shared__ float s[64];
    if (threadIdx.x < 64) s[threadIdx.x] = sc[threadIdx.x];
    __syncthreads();
    const int total4 = 2*32*CHS/4;
    const int Q = CHS/4;
    for (int i = blockIdx.x*256 + threadIdx.x; i < total4; i += gridDim.x*256) {
        float4 v = ((const float4*)out)[i];
        const int c = (i / Q) & 31;
        const float scale = s[c], shift = s[32+c];
        v.x = fmaf(v.x, scale, shift);
        v.y = fmaf(v.y, scale, shift);
        v.z = fmaf(v.z, scale, shift);
        v.w = fmaf(v.w, scale, shift);
        ((float4*)out)[i] = v;
    }
}

extern "C" void kernel_launch(void* const* d_in, const int* in_sizes, int n_in,
                              void* d_out, int out_size, void* d_ws, size_t ws_size,
                              hipStream_t stream) {
    const float* x        = (const float*)d_in[0];
    const float* spacings = (const float*)d_in[1];
    const float* theta_w  = (const float*)d_in[2];
    const float* theta_b  = (const float*)d_in[3];
    const float* phi_w    = (const float*)d_in[4];
    const float* phi_b    = (const float*)d_in[5];
    const float* g_w      = (const float*)d_in[6];
    const float* g_b      = (const float*)d_in[7];
    const float* Ww       = (const float*)d_in[8];
    const float* Wb       = (const float*)d_in[9];
    const float* gamma    = (const float*)d_in[10];
    const float* beta     = (const float*)d_in[11];
    float* out   = (float*)d_out;
    char*  frags = (char*)d_ws;                         // WSFRAG bytes
    float* part  = (float*)((char*)d_ws + WSFRAG);      // ROWS*64 floats
    float* part2 = part + ROWS*64;                      // 256*64 floats
    float* sc    = part2 + 256*64;                      // 64 floats

    hipLaunchKernelGGL(k0_frag, dim3(1), dim3(256), 0, stream, theta_w, phi_w, Ww, frags);
    hipLaunchKernelGGL(k1_row, dim3(ROWS), dim3(256), 0, stream,
                       x, spacings, theta_b, phi_b, g_w, g_b, Wb, frags, out, part);
    hipLaunchKernelGGL(k2a, dim3(256), dim3(256), 0, stream, part, part2);
    hipLaunchKernelGGL(k2b, dim3(1), dim3(256), 0, stream, part2, gamma, beta, sc);
    hipLaunchKernelGGL(k3_norm, dim3(4096), dim3(256), 0, stream, out, sc);
}